// Round 1
// baseline (15.843 us; speedup 1.0000x reference)
//
#include <hip/hip_runtime.h>
#include <hip/hip_bf16.h>

// out[bt][s][d] = W_T[text[bt][s]][d] + b[d] + pe[s][d]
// B=4, S=2048, D=1024, VOCAB=50257. All f32 except text (int32).
// One block per token row (8192 rows), 256 threads x float4 = 4KB row.

#define D_MODEL 1024
#define D4 (D_MODEL / 4)   // 256
#define SEQ 2048

__global__ __launch_bounds__(256) void embed_kernel(
    const int* __restrict__ text,      // [8192]
    const float4* __restrict__ W_T,    // [50257][256]
    const float4* __restrict__ bias,   // [256]
    const float4* __restrict__ pe,     // [4096][256] (use first 2048 rows)
    float4* __restrict__ out)          // [8192][256]
{
    const int token = blockIdx.x;       // 0..8191
    const int d4    = threadIdx.x;      // 0..255
    const int s     = token & (SEQ - 1);

    const int row = text[token];        // uniform within block -> cached broadcast

    const float4 w = W_T[(size_t)row * D4 + d4];
    const float4 bb = bias[d4];
    const float4 p = pe[(size_t)s * D4 + d4];

    float4 o;
    o.x = w.x + bb.x + p.x;
    o.y = w.y + bb.y + p.y;
    o.z = w.z + bb.z + p.z;
    o.w = w.w + bb.w + p.w;

    out[(size_t)token * D4 + d4] = o;
}

extern "C" void kernel_launch(void* const* d_in, const int* in_sizes, int n_in,
                              void* d_out, int out_size, void* d_ws, size_t ws_size,
                              hipStream_t stream) {
    const int*    text = (const int*)d_in[0];      // [4*2048]
    const float4* W_T  = (const float4*)d_in[1];   // [50257*1024] f32
    const float4* bias = (const float4*)d_in[2];   // [1024] f32
    const float4* pe   = (const float4*)d_in[3];   // [1*4096*1024] f32
    float4* out = (float4*)d_out;

    const int n_tokens = in_sizes[0];              // 8192
    embed_kernel<<<n_tokens, 256, 0, stream>>>(text, W_T, bias, pe, out);
}